// Round 1
// baseline (613.978 us; speedup 1.0000x reference)
//
#include <hip/hip_runtime.h>

// CausalSGU: out[b,m,c] = (sum_{n<=m} w[h,m,n]*LN(gate)[b,n,c] + bias[h,m]) * res[b,m,c]
//   x: (4,2048,2048) fp32; res = x[:,:,0:1024], gate = x[:,:,1024:2048]
//   weight: (4,2048,2048) fp32 (tril-masked), bias: (4,2048), gamma/beta: (1024)
// Round 1: correct fp32 SIMT tiled baseline. MFMA bf16 planned next.

constexpr int Bb  = 4;
constexpr int Nn  = 2048;
constexpr int DX  = 2048;
constexpr int Hh  = 4;
constexpr int GDg = 1024;   // gate width
constexpr int DHh = 256;    // per-head width

constexpr int BM = 64, BD = 64, BK = 32;

__global__ __launch_bounds__(256) void ln_stats_kernel(const float* __restrict__ x,
                                                       float* __restrict__ mu,
                                                       float* __restrict__ rstd) {
    int row = blockIdx.x;                       // b*N + n
    const float4* xr = reinterpret_cast<const float4*>(x + (size_t)row * DX + GDg);
    int t = threadIdx.x;                        // 256 threads, 4 floats each
    float4 v = xr[t];
    float s  = v.x + v.y + v.z + v.w;
    float ss = v.x*v.x + v.y*v.y + v.z*v.z + v.w*v.w;
#pragma unroll
    for (int off = 32; off >= 1; off >>= 1) {
        s  += __shfl_down(s, off, 64);
        ss += __shfl_down(ss, off, 64);
    }
    __shared__ float sm[8];
    int wv = t >> 6;
    if ((t & 63) == 0) { sm[wv] = s; sm[4 + wv] = ss; }
    __syncthreads();
    if (t == 0) {
        float S  = sm[0] + sm[1] + sm[2] + sm[3];
        float SS = sm[4] + sm[5] + sm[6] + sm[7];
        float m   = S * (1.0f / GDg);
        float var = SS * (1.0f / GDg) - m * m;
        mu[row]   = m;
        rstd[row] = rsqrtf(var + 1e-5f);
    }
}

__global__ __launch_bounds__(256) void sgu_matmul_kernel(
    const float* __restrict__ x, const float* __restrict__ w,
    const float* __restrict__ bias, const float* __restrict__ gamma,
    const float* __restrict__ beta, const float* __restrict__ mu,
    const float* __restrict__ rstd, float* __restrict__ out)
{
    const int b  = blockIdx.z;
    const int h  = blockIdx.y;
    const int mt = blockIdx.x >> 2;    // N/BM = 32 m-tiles
    const int dt = blockIdx.x & 3;     // DH/BD = 4 d-tiles
    const int m0 = mt * BM;
    const int d0 = dt * BD;

    __shared__ float Wt[BM][BK + 1];   // +1 pad: kills bank conflicts on column reads
    __shared__ float Gt[BK][BD + 1];

    const int t  = threadIdx.x;
    const int tx = t & 15;             // d-direction (4 cols each)
    const int ty = t >> 4;             // m-direction (4 rows each)

    float acc[4][4] = {};

    const float* wbase = w + ((size_t)h * Nn + m0) * Nn;
    const float* xb    = x + (size_t)b * Nn * DX;

    const int nk = (m0 + BM) / BK;     // causal: only k-tiles with n0 < m0+BM

    const int rw = t >> 3;             // W-tile row 0..31 (and +32)
    const int cw = (t & 7) * 4;        // W-tile col
    const int rg = t >> 4;             // G-tile row 0..15 (and +16)
    const int cg = (t & 15) * 4;       // G-tile col

    const int cbase = h * DHh + d0;    // channel base within gate's 1024

    for (int kt = 0; kt < nk; ++kt) {
        const int n0 = kt * BK;
#pragma unroll
        for (int rr = 0; rr < 2; ++rr) {
            int i = rw + rr * 32;
            int m = m0 + i;
            float4 wv = *reinterpret_cast<const float4*>(wbase + (size_t)i * Nn + n0 + cw);
            float vals[4] = {wv.x, wv.y, wv.z, wv.w};
#pragma unroll
            for (int q = 0; q < 4; ++q) {
                int n = n0 + cw + q;
                Wt[i][cw + q] = (n <= m) ? vals[q] : 0.0f;   // tril mask at load
            }
        }
#pragma unroll
        for (int rr = 0; rr < 2; ++rr) {
            int k = rg + rr * 16;
            int n = n0 + k;
            float muv = mu[b * Nn + n];
            float rs  = rstd[b * Nn + n];
            float4 gv = *reinterpret_cast<const float4*>(xb + (size_t)n * DX + GDg + cbase + cg);
            float4 gm = *reinterpret_cast<const float4*>(gamma + cbase + cg);
            float4 bt = *reinterpret_cast<const float4*>(beta  + cbase + cg);
            Gt[k][cg + 0] = (gv.x - muv) * rs * gm.x + bt.x;
            Gt[k][cg + 1] = (gv.y - muv) * rs * gm.y + bt.y;
            Gt[k][cg + 2] = (gv.z - muv) * rs * gm.z + bt.z;
            Gt[k][cg + 3] = (gv.w - muv) * rs * gm.w + bt.w;
        }
        __syncthreads();
#pragma unroll
        for (int k = 0; k < BK; ++k) {
            float wr[4], gr[4];
#pragma unroll
            for (int i = 0; i < 4; ++i) wr[i] = Wt[ty * 4 + i][k];
#pragma unroll
            for (int j = 0; j < 4; ++j) gr[j] = Gt[k][tx * 4 + j];
#pragma unroll
            for (int i = 0; i < 4; ++i)
#pragma unroll
                for (int j = 0; j < 4; ++j)
                    acc[i][j] = fmaf(wr[i], gr[j], acc[i][j]);
        }
        __syncthreads();
    }

    // epilogue: (+bias) * res, res = x[b, m, cbase + ...] (channels 0..1023)
#pragma unroll
    for (int i = 0; i < 4; ++i) {
        int m = m0 + ty * 4 + i;
        float bv = bias[h * Nn + m];
        float4 rv = *reinterpret_cast<const float4*>(xb + (size_t)m * DX + cbase + tx * 4);
        float4 ov;
        ov.x = (acc[i][0] + bv) * rv.x;
        ov.y = (acc[i][1] + bv) * rv.y;
        ov.z = (acc[i][2] + bv) * rv.z;
        ov.w = (acc[i][3] + bv) * rv.w;
        *reinterpret_cast<float4*>(out + ((size_t)b * Nn + m) * GDg + cbase + tx * 4) = ov;
    }
}

extern "C" void kernel_launch(void* const* d_in, const int* in_sizes, int n_in,
                              void* d_out, int out_size, void* d_ws, size_t ws_size,
                              hipStream_t stream) {
    const float* x     = (const float*)d_in[0];
    const float* w     = (const float*)d_in[1];
    const float* bias  = (const float*)d_in[2];
    const float* gamma = (const float*)d_in[3];
    const float* beta  = (const float*)d_in[4];
    float* out  = (float*)d_out;
    float* mu   = (float*)d_ws;            // B*N floats
    float* rstd = mu + Bb * Nn;            // B*N floats  (64 KB total)

    ln_stats_kernel<<<Bb * Nn, 256, 0, stream>>>(x, mu, rstd);

    dim3 grid((Nn / BM) * (DHh / BD), Hh, Bb);   // 128 x 4 x 4 = 2048 blocks
    sgu_matmul_kernel<<<grid, 256, 0, stream>>>(x, w, bias, gamma, beta, mu, rstd, out);
}

// Round 5
// 225.847 us; speedup vs baseline: 2.7186x; 2.7186x over previous
//
#include <hip/hip_runtime.h>
#include <hip/hip_bf16.h>

constexpr int Bb = 4;
constexpr int Nn = 2048;
constexpr int DX = 2048;
constexpr int GD = 1024;   // gate width
constexpr int DH = 256;    // per-head width
constexpr int BM = 128, BD = 128, BK = 32;

typedef short short8v __attribute__((ext_vector_type(8)));
typedef float f32x4   __attribute__((ext_vector_type(4)));

static __device__ __forceinline__ short f2bf(float f) {
    return __builtin_bit_cast(short, __float2bfloat16(f));   // RNE
}

// one wave per row: mean / rstd of gate half
__global__ __launch_bounds__(256) void ln_stats_kernel(const float* __restrict__ x,
                                                       float* __restrict__ mu,
                                                       float* __restrict__ rstd) {
    int t = threadIdx.x;
    int row = blockIdx.x * 4 + (t >> 6);
    int lane = t & 63;
    const float4* xr = reinterpret_cast<const float4*>(x + (size_t)row * DX + GD);
    float s = 0.f, ss = 0.f;
#pragma unroll
    for (int q = 0; q < 4; ++q) {
        float4 v = xr[q * 64 + lane];
        s  += v.x + v.y + v.z + v.w;
        ss += v.x*v.x + v.y*v.y + v.z*v.z + v.w*v.w;
    }
#pragma unroll
    for (int off = 32; off >= 1; off >>= 1) {
        s  += __shfl_down(s,  off, 64);
        ss += __shfl_down(ss, off, 64);
    }
    if (lane == 0) {
        float m   = s * (1.f / GD);
        float var = ss * (1.f / GD) - m * m;
        mu[row]   = m;
        rstd[row] = rsqrtf(var + 1e-5f);
    }
}

__global__ __launch_bounds__(256, 2) void sgu_mfma_kernel(
    const float* __restrict__ x, const float* __restrict__ w,
    const float* __restrict__ bias, const float* __restrict__ gamma,
    const float* __restrict__ beta, const float* __restrict__ mu,
    const float* __restrict__ rstd, float* __restrict__ out)
{
    __shared__ __align__(16) short Ws[2][BM * BK];   // [row 128][k 32] bf16, XOR-swizzled
    __shared__ __align__(16) short Gs[2][BK * BD];   // [k 32][c 128]  bf16, XOR-swizzled

    const int t  = threadIdx.x;
    const int bx = blockIdx.x;              // dc(2) | h(4) | b(4)
    const int dc = bx & 1;
    const int h  = (bx >> 1) & 3;
    const int b  = bx >> 3;
    const int y  = blockIdx.y;              // heavy-first, pair-balanced m order
    const int mt = (y < 8) ? (15 - 2 * y) : ((y - 8) * 2);
    const int m0 = mt * BM;
    const int cb = h * DH + dc * BD;        // channel base in [0,1024)
    const int nk = 4 * mt + 4;              // causal k-tiles

    const int lane = t & 63;
    const int wv = t >> 6;
    const int wm = wv >> 1, wc = wv & 1;    // 2x2 wave grid, 64x64 per wave
    const int g  = lane >> 4;               // k-group
    const int lr = lane & 15;

    // staging roles
    const int sw_row = t >> 1;              // W row 0..127
    const int sw_kh  = t & 1;               // W k-half
    const int sg_k   = t >> 3;              // G k row 0..31
    const int sg_cs  = t & 7;               // G c-subtile 0..7 (16 ch each)

    const float* xb   = x + (size_t)b * Nn * DX;
    const float* wrow = w + ((size_t)h * Nn + m0 + sw_row) * Nn + sw_kh * 16;
    const float* gsrc = xb + GD + cb + sg_cs * 16;

    // gamma/beta for this thread's staged channels (fixed across k-tiles)
    float4 gmv[4], btv[4];
#pragma unroll
    for (int q = 0; q < 4; ++q) {
        gmv[q] = *reinterpret_cast<const float4*>(gamma + cb + sg_cs * 16 + q * 4);
        btv[q] = *reinterpret_cast<const float4*>(beta  + cb + sg_cs * 16 + q * 4);
    }

    f32x4 acc[4][4] = {};
    float4 wreg[4], greg[4];
    float muv = 0.f, rsv = 0.f;

    auto LOADT = [&](int kt) {
        const int n0 = kt * BK;
#pragma unroll
        for (int q = 0; q < 4; ++q)
            wreg[q] = *reinterpret_cast<const float4*>(wrow + n0 + q * 4);
        const float* gp = gsrc + (size_t)(n0 + sg_k) * DX;
#pragma unroll
        for (int q = 0; q < 4; ++q)
            greg[q] = *reinterpret_cast<const float4*>(gp + q * 4);
        muv = mu[b * Nn + n0 + sg_k];
        rsv = rstd[b * Nn + n0 + sg_k];
    };

    auto STAGE = [&](int buf, int kt) {
        const int n0 = kt * BK;
        // --- W: tril mask + cvt, two swizzled b128 writes ---
        const int m = m0 + sw_row;
        short8v wlo, whi;
#pragma unroll
        for (int q = 0; q < 4; ++q) {
            float vv[4] = {wreg[q].x, wreg[q].y, wreg[q].z, wreg[q].w};
#pragma unroll
            for (int e = 0; e < 4; ++e) {
                int i = q * 4 + e;
                int n = n0 + sw_kh * 16 + i;
                short bfv = f2bf((n <= m) ? vv[e] : 0.f);
                if (i < 8) wlo[i] = bfv; else whi[i - 8] = bfv;
            }
        }
        char* wl = (char*)&Ws[buf][0];
        unsigned wb = (unsigned)(sw_row * 64 + sw_kh * 32);
        unsigned sz = ((unsigned)(sw_row >> 1) & 3u) << 4;
        *reinterpret_cast<short8v*>(wl + ((wb)      ^ sz)) = wlo;
        *reinterpret_cast<short8v*>(wl + ((wb + 16) ^ sz)) = whi;
        // --- G: LN + cvt, two swizzled b128 writes ---
        short8v glo, ghi;
#pragma unroll
        for (int q = 0; q < 4; ++q) {
            float vv[4] = {greg[q].x, greg[q].y, greg[q].z, greg[q].w};
            float gm[4] = {gmv[q].x, gmv[q].y, gmv[q].z, gmv[q].w};
            float bt[4] = {btv[q].x, btv[q].y, btv[q].z, btv[q].w};
#pragma unroll
            for (int e = 0; e < 4; ++e) {
                int i = q * 4 + e;
                short bfv = f2bf((vv[e] - muv) * rsv * gm[e] + bt[e]);
                if (i < 8) glo[i] = bfv; else ghi[i - 8] = bfv;
            }
        }
        char* glp = (char*)&Gs[buf][0];
        unsigned gb = (unsigned)(sg_k * 256 + sg_cs * 32);
        unsigned gz = ((unsigned)(sg_k >> 3) & 3u) << 5;
        *reinterpret_cast<short8v*>(glp + ((gb)      ^ gz)) = glo;
        *reinterpret_cast<short8v*>(glp + ((gb + 16) ^ gz)) = ghi;
    };

    auto COMPUTE = [&](int buf) {
        const char* wl = (const char*)&Ws[buf][0];
        const char* glp = (const char*)&Gs[buf][0];
        short8v af[4];
#pragma unroll
        for (int fi = 0; fi < 4; ++fi) {
            int row = wm * 64 + fi * 16 + lr;
            unsigned off = (unsigned)(row * 64 + g * 16);
            off ^= ((unsigned)(row >> 1) & 3u) << 4;
            af[fi] = *reinterpret_cast<const short8v*>(wl + off);
        }
        short8v bf[4];
#pragma unroll
        for (int fj = 0; fj < 4; ++fj) {
            int c = wc * 64 + fj * 16 + lr;
#pragma unroll
            for (int j = 0; j < 8; ++j) {
                int row = g * 8 + j;
                unsigned off = (unsigned)(row * 256 + c * 2);
                off ^= ((unsigned)(row >> 3) & 3u) << 5;
                bf[fj][j] = *reinterpret_cast<const short*>(glp + off);
            }
        }
#pragma unroll
        for (int fi = 0; fi < 4; ++fi)
#pragma unroll
            for (int fj = 0; fj < 4; ++fj)
                acc[fi][fj] = __builtin_amdgcn_mfma_f32_16x16x32_bf16(
                    af[fi], bf[fj], acc[fi][fj], 0, 0, 0);
    };

    LOADT(0);
    STAGE(0, 0);
    __syncthreads();
    int cur = 0;
    for (int kt = 0; kt < nk; ++kt) {
        const bool more = (kt + 1 < nk);
        if (more) LOADT(kt + 1);            // issue early — hides under MFMA
        COMPUTE(cur);
        if (more) STAGE(cur ^ 1, kt + 1);   // write late
        __syncthreads();
        cur ^= 1;
    }

    // epilogue: (+bias) * res
#pragma unroll
    for (int fi = 0; fi < 4; ++fi) {
#pragma unroll
        for (int r = 0; r < 4; ++r) {
            int m = m0 + wm * 64 + fi * 16 + g * 4 + r;
            float bv = bias[h * Nn + m];
            const float* resrow = xb + (size_t)m * DX + cb;
            float* orow = out + ((size_t)b * Nn + m) * GD + cb;
#pragma unroll
            for (int fj = 0; fj < 4; ++fj) {
                int c = wc * 64 + fj * 16 + lr;
                orow[c] = (acc[fi][fj][r] + bv) * resrow[c];
            }
        }
    }
}

extern "C" void kernel_launch(void* const* d_in, const int* in_sizes, int n_in,
                              void* d_out, int out_size, void* d_ws, size_t ws_size,
                              hipStream_t stream) {
    const float* x     = (const float*)d_in[0];
    const float* w     = (const float*)d_in[1];
    const float* bias  = (const float*)d_in[2];
    const float* gamma = (const float*)d_in[3];
    const float* beta  = (const float*)d_in[4];
    float* out  = (float*)d_out;
    float* mu   = (float*)d_ws;            // B*N floats
    float* rstd = mu + Bb * Nn;            // B*N floats (64 KB total)

    ln_stats_kernel<<<Bb * Nn / 4, 256, 0, stream>>>(x, mu, rstd);

    dim3 grid(32, 16, 1);                  // x: dc|h|b, y: balanced m-tile order
    sgu_mfma_kernel<<<grid, 256, 0, stream>>>(x, w, bias, gamma, beta, mu, rstd, out);
}